// Round 5
// baseline (190.420 us; speedup 1.0000x reference)
//
#include <hip/hip_runtime.h>

// F0 via autocorrelation argmax — round 18: persistent grid + r17 pair body.
//   SR=16000, HOP=256, FRAME_LEN=512, pad=256, T=163840, B=64, n_frames=641
//   lags p in [32,256). argmax of RAW autocorrelation == reference argmax.
//
// Evidence r13-r17: single-shot grids complete at ~146 WG/us regardless of
// body (r13/15/16: 10256 WG in 70-77us, ~1.5 blocks/CU resident) -> WG
// dispatch rate caps residency. r14's "occupancy didn't help" was confounded
// (launch_bounds(256,8) -> 32 VGPR cripple). r17 proved the 2-frame
// interleaved body runs a pair in 4.3us (1.5x one frame, good ILP) at 112
// VGPR, but 5128 one-shot 51.2KB blocks starved residency (12%). r18 runs
// the SAME pair body in a persistent grid: 768 blocks (3/CU LDS cap) x 4
// waves, each wave loops 6-7 contiguous pairs. Ramp ~5us, then 12 waves/CU.
// DS-service floor ~480cyc/frame -> ~37us chip-wide; predict 45-55us.
//
// Per-frame numerics bit-identical to r16/r17 -> absmax 0.0 preserved.
// Reductions on VALU (DPP quad_perm/row_ror + permlane16/32_swap; fail-safe:
// wrong orientation inflates v2 -> gates reject -> exact tier-3).
// NC=15 (c=15 B-frags all zero -> +0.0 exactly).
//
// GEMM cast (validated r8-r17, absmax 0.0): y = frame zero-extended,
//   A[m,k]=y[k-16m], B[k,n]=y[k+32+n] => D[m,n]=AC[32+16m+n]
//   15 mfma_f32_16x16x32_f16, two parity LDS copies for B-align.
// Tiers: E1 = 2^-10*Q + 0.05 ; tier-2 double-f16 split E2 = 1e-4*Q + 0.02 ;
// tier-3 fp64 register tile exact (cold).

#define SR_F 16000.0f
#define HOP 256
#define FRAME_LEN 512
#define PAD 256
#define T_LEN 163840
#define N_FRAMES 641
#define TOTAL (64 * N_FRAMES)   // 41024
#define HALF (TOTAL / 2)        // 20512 pairs
#define MIN_PERIOD 32
#define N_LAGS 224
#define WPB 4            // waves per block, TWO frames per wave per iteration
#define NC 15            // K-steps: c=15 contributes exactly zero
#define NBLK 768         // 3 blocks/CU (51.2KB LDS each) — fully resident
#define NSLOT (NBLK * WPB)          // 3072 wave slots
#define EXTRA (HALF - 6 * NSLOT)    // 2080 slots carry 7 pairs, rest 6

typedef _Float16 half8 __attribute__((ext_vector_type(8)));
typedef float floatx4 __attribute__((ext_vector_type(4)));
typedef unsigned int uint2v __attribute__((ext_vector_type(2)));

__device__ __forceinline__ int swz(int q) { return q ^ ((q >> 3) & 7); }

__device__ __forceinline__ unsigned int pkh(float a, float b) {
    unsigned short ha = __builtin_bit_cast(unsigned short, (_Float16)a);
    unsigned short hb = __builtin_bit_cast(unsigned short, (_Float16)b);
    return (unsigned int)ha | ((unsigned int)hb << 16);
}

// ---- cross-lane on the VALU pipe (keep the DS unit free) ----
#define DPP_XOR1 0xB1    // quad_perm [1,0,3,2]
#define DPP_XOR2 0x4E    // quad_perm [2,3,0,1]
#define DPP_ROR4 0x124   // row_ror:4
#define DPP_ROR8 0x128   // row_ror:8

template <int CTRL> __device__ __forceinline__ int dppi(int x) {
    return __builtin_amdgcn_update_dpp(0, x, CTRL, 0xF, 0xF, false);
}
template <int CTRL> __device__ __forceinline__ float dppf(float x) {
    return __builtin_bit_cast(float, dppi<CTRL>(__builtin_bit_cast(int, x)));
}

// permlane swaps: contract — pr[0]+pr[1] == self+partner;
// (sel ? pr[0] : pr[1]) == partner, sel = oddrow (16) / upper half (32).
__device__ __forceinline__ uint2v pl16sw(unsigned int x, bool sel) {
#if __has_builtin(__builtin_amdgcn_permlane16_swap)
    (void)sel;
    return __builtin_amdgcn_permlane16_swap(x, x, false, false);
#else
    unsigned int p = (unsigned int)__shfl_xor((int)x, 16);
    uint2v r; r[0] = sel ? p : x; r[1] = sel ? x : p; return r;
#endif
}
__device__ __forceinline__ uint2v pl32sw(unsigned int x, bool sel) {
#if __has_builtin(__builtin_amdgcn_permlane32_swap)
    (void)sel;
    return __builtin_amdgcn_permlane32_swap(x, x, false, false);
#else
    unsigned int p = (unsigned int)__shfl_xor((int)x, 32);
    uint2v r; r[0] = sel ? p : x; r[1] = sel ? x : p; return r;
#endif
}

// full-wave sum, zero DS ops
__device__ __forceinline__ float wave_sum(float x, bool oddrow, bool hihalf) {
    x += dppf<DPP_XOR1>(x);
    x += dppf<DPP_XOR2>(x);
    x += dppf<DPP_ROR4>(x);
    x += dppf<DPP_ROR8>(x);
    uint2v p = pl16sw(__builtin_bit_cast(unsigned int, x), oddrow);
    x = __builtin_bit_cast(float, p[0]) + __builtin_bit_cast(float, p[1]);
    p = pl32sw(__builtin_bit_cast(unsigned int, x), hihalf);
    x = __builtin_bit_cast(float, p[0]) + __builtin_bit_cast(float, p[1]);
    return x;
}

__device__ __forceinline__
void top2_comb(float& v1, int& i1, float& v2, float ov1, int oi1, float ov2) {
    bool take = (ov1 > v1) || (ov1 == v1 && oi1 < i1);
    float lose = take ? v1 : ov1;
    if (take) { v1 = ov1; i1 = oi1; }
    v2 = fmaxf(fmaxf(v2, ov2), lose);
}

template <int CTRL> __device__ __forceinline__
void top2_dpp(float& v1, int& i1, float& v2) {
    float ov1 = dppf<CTRL>(v1);
    int   oi1 = dppi<CTRL>(i1);
    float ov2 = dppf<CTRL>(v2);
    top2_comb(v1, i1, v2, ov1, oi1, ov2);
}

// per-lane top2 over 4 regs, then full-wave combine — zero DS ops
__device__ __forceinline__
void top2_full(floatx4 acc, int qd, int nn, bool oddrow, bool hihalf,
               float& v1, int& i1, float& v2) {
    v1 = acc[0];
    i1 = 64*qd + nn;
    v2 = -__builtin_inff();
    #pragma unroll
    for (int r = 1; r < 4; ++r) {
        float cv = (4*qd + r < 14) ? acc[r] : -__builtin_inff();
        bool take = (cv > v1);
        float lose = take ? v1 : cv;
        if (take) { v1 = cv; i1 = 64*qd + 16*r + nn; }
        v2 = fmaxf(v2, lose);
    }
    top2_dpp<DPP_XOR1>(v1, i1, v2);
    top2_dpp<DPP_XOR2>(v1, i1, v2);
    top2_dpp<DPP_ROR4>(v1, i1, v2);
    top2_dpp<DPP_ROR8>(v1, i1, v2);
    {   // stage 16 via permlane16_swap
        uint2v a = pl16sw(__builtin_bit_cast(unsigned int, v1), oddrow);
        uint2v b = pl16sw((unsigned int)i1, oddrow);
        uint2v c = pl16sw(__builtin_bit_cast(unsigned int, v2), oddrow);
        float ov1 = __builtin_bit_cast(float, oddrow ? a[0] : a[1]);
        int   oi1 = (int)(oddrow ? b[0] : b[1]);
        float ov2 = __builtin_bit_cast(float, oddrow ? c[0] : c[1]);
        top2_comb(v1, i1, v2, ov1, oi1, ov2);
    }
    {   // stage 32 via permlane32_swap
        uint2v a = pl32sw(__builtin_bit_cast(unsigned int, v1), hihalf);
        uint2v b = pl32sw((unsigned int)i1, hihalf);
        uint2v c = pl32sw(__builtin_bit_cast(unsigned int, v2), hihalf);
        float ov1 = __builtin_bit_cast(float, hihalf ? a[0] : a[1]);
        int   oi1 = (int)(hihalf ? b[0] : b[1]);
        float ov2 = __builtin_bit_cast(float, hihalf ? c[0] : c[1]);
        top2_comb(v1, i1, v2, ov1, oi1, ov2);
    }
}

// stage parity copies: even (elem e = Y[e-240]) + odd (elem e = Y[e-239])
__device__ __forceinline__ void write_copies(unsigned int* e, unsigned int* o,
                                             unsigned int u10, unsigned int u11,
                                             unsigned int u20, unsigned int u21,
                                             int lane) {
    e[120 + 2*lane] = u10;  e[121 + 2*lane] = u11;
    e[248 + 2*lane] = u20;  e[249 + 2*lane] = u21;
    unsigned int a  = __shfl(u10, (lane + 1) & 63);
    unsigned int bb = __shfl(u20, (lane + 1) & 63);
    unsigned int n1 = (lane == 63) ? bb : a;
    unsigned int n2 = (lane == 63) ? 0u : bb;
    o[120 + 2*lane] = (u10 >> 16) | (u11 << 16);
    o[121 + 2*lane] = (u11 >> 16) | (n1 << 16);
    o[248 + 2*lane] = (u20 >> 16) | (u21 << 16);
    o[249 + 2*lane] = (u21 >> 16) | (n2 << 16);
    if (lane == 0) o[119] = u10 << 16;   // {Y[-1]=0, Y[0]}
}

__device__ __forceinline__ void emit(float* out, int bf, int i1) {
    float period = (float)(i1 + MIN_PERIOD);
    float f0 = SR_F / (period + 1e-8f);
    out[bf] = fminf(fmaxf(f0, 50.0f), 500.0f);
}

// ---- tier-2 + tier-3 for one frame (cold; inlined twice) ----
__device__ __forceinline__ void finish_frame(
    const float* __restrict__ x, int base, bool fast, int bf,
    float* __restrict__ out,
    unsigned int* ye, unsigned int* yo, unsigned int* le, unsigned int* loo,
    float4 c1, float4 c2, floatx4 acc, float qen, int lane,
    int qd, int nn, int par, int wA0, int wB0, int seg,
    bool oddrow, bool hihalf) {

    const unsigned int* ybh = par ? yo : ye;
    const unsigned int* ybl = par ? loo : le;
    const bool s0 = (seg & 1), s1 = (seg & 2), s2 = (seg & 4), s3 = (seg & 8);

    // ==== tier-2: double-f16 split, +30 MFMA (hi*lo + lo*hi) ====
    le[lane] = 0u; loo[lane] = 0u;
    if (lane < 56) { le[64 + lane] = 0u; loo[64 + lane] = 0u; }
    if (lane < 25) { le[375 + lane] = 0u; loo[375 + lane] = 0u; }
    if (fast) {
        float l0 = c1.x - (float)(_Float16)c1.x;
        float l1 = c1.y - (float)(_Float16)c1.y;
        float l2 = c1.z - (float)(_Float16)c1.z;
        float l3 = c1.w - (float)(_Float16)c1.w;
        float l4 = c2.x - (float)(_Float16)c2.x;
        float l5 = c2.y - (float)(_Float16)c2.y;
        float l6 = c2.z - (float)(_Float16)c2.z;
        float l7 = c2.w - (float)(_Float16)c2.w;
        write_copies(le, loo, pkh(l0, l1), pkh(l2, l3),
                              pkh(l4, l5), pkh(l6, l7), lane);
    } else {
        for (int t = lane; t < FRAME_LEN; t += 64) {
            int idxr = base + t;
            if (idxr < 0) idxr = -idxr;
            if (idxr >= T_LEN) idxr = 2 * (T_LEN - 1) - idxr;
            float v = x[idxr];
            float l = v - (float)(_Float16)v;
            unsigned short h = __builtin_bit_cast(unsigned short, (_Float16)l);
            ((unsigned short*)le)[240 + t] = h;
            ((unsigned short*)loo)[239 + t] = h;
        }
    }
    __threadfence_block();

    #pragma unroll
    for (int c = 0; c < NC; ++c) {              // hi * lo
        uint4 au = *(const uint4*)(ye + (wA0 + 16*c));
        const unsigned int* p = ybl + (wB0 + 16*c);
        uint4 bu; bu.x = p[0]; bu.y = p[1]; bu.z = p[2]; bu.w = p[3];
        acc = __builtin_amdgcn_mfma_f32_16x16x32_f16(
            __builtin_bit_cast(half8, au), __builtin_bit_cast(half8, bu),
            acc, 0, 0, 0);
    }
    #pragma unroll
    for (int c = 0; c < NC; ++c) {              // lo * hi
        uint4 au = *(const uint4*)(le + (wA0 + 16*c));
        const unsigned int* p = ybh + (wB0 + 16*c);
        uint4 bu; bu.x = p[0]; bu.y = p[1]; bu.z = p[2]; bu.w = p[3];
        acc = __builtin_amdgcn_mfma_f32_16x16x32_f16(
            __builtin_bit_cast(half8, au), __builtin_bit_cast(half8, bu),
            acc, 0, 0, 0);
    }

    float v1, v2; int i1;
    top2_full(acc, qd, nn, oddrow, hihalf, v1, i1, v2);

    const float E2 = 1.0e-4f * qen + 0.02f;
    if (v1 - v2 > 2.0f * E2) {
        if (lane == 0) emit(out, bf, i1);
        return;
    }

    // ============ tier-3: fp64 register tile (exact) ============
    float* sw = (float*)ye;   // 576 floats over ye+yo (clobbers; re-staged next iter)
    if (fast) {
        const float4* g4 = (const float4*)(x + base);   // L2-hot reload
        ((float4*)sw)[swz(lane)]      = g4[lane];
        ((float4*)sw)[swz(lane + 64)] = g4[lane + 64];
        if (lane < 16) ((float4*)sw)[swz(lane + 128)] = make_float4(0.f,0.f,0.f,0.f);
    } else {
        for (int t = lane; t < FRAME_LEN; t += 64) {
            int idxr = base + t;
            if (idxr < 0) idxr = -idxr;
            if (idxr >= T_LEN) idxr = 2 * (T_LEN - 1) - idxr;
            sw[(swz(t >> 2) << 2) | (t & 3)] = x[idxr];
        }
        int t = FRAME_LEN + lane;
        sw[(swz(t >> 2) << 2) | (t & 3)] = 0.0f;
    }
    __threadfence_block();

    const float4* s4 = (const float4*)sw;
    double dtot[4];
    #pragma unroll
    for (int r = 0; r < 4; ++r) {
        const int g  = (r << 2) + qd;
        const int p0 = MIN_PERIOD + (g << 4);
        double dacc[16];
        #pragma unroll
        for (int j = 0; j < 16; ++j) dacc[j] = 0.0;
        if (g < 14) {
            const int n16 = (FRAME_LEN - p0 + 15) >> 4;
            #pragma unroll
            for (int k = 0; k < 2; ++k) {
                const int ch = seg + (k << 4);
                if (ch < n16) {
                    const int t  = ch << 4;
                    const int qa = t >> 2;
                    const int qw = (t + p0) >> 2;
                    float a[16], w[32];
                    #pragma unroll
                    for (int u = 0; u < 4; ++u) {
                        float4 v = s4[swz(qa + u)];
                        a[4*u+0]=v.x; a[4*u+1]=v.y; a[4*u+2]=v.z; a[4*u+3]=v.w;
                    }
                    #pragma unroll
                    for (int u = 0; u < 8; ++u) {
                        float4 v = s4[swz(qw + u)];
                        w[4*u+0]=v.x; w[4*u+1]=v.y; w[4*u+2]=v.z; w[4*u+3]=v.w;
                    }
                    #pragma unroll
                    for (int j = 0; j < 16; ++j) {
                        #pragma unroll
                        for (int i = 0; i < 16; ++i)
                            dacc[j] = fma((double)a[i], (double)w[i + j], dacc[j]);
                    }
                }
            }
        }
        double u8[8], u4[4], u2[2], dtotal;
        #pragma unroll
        for (int i = 0; i < 8; ++i) {
            double lo = dacc[2*i], hi = dacc[2*i+1];
            double keep = s0 ? hi : lo, send = s0 ? lo : hi;
            u8[i] = keep + __shfl_xor(send, 1);
        }
        #pragma unroll
        for (int i = 0; i < 4; ++i) {
            double lo = u8[2*i], hi = u8[2*i+1];
            double keep = s1 ? hi : lo, send = s1 ? lo : hi;
            u4[i] = keep + __shfl_xor(send, 2);
        }
        #pragma unroll
        for (int i = 0; i < 2; ++i) {
            double lo = u4[2*i], hi = u4[2*i+1];
            double keep = s2 ? hi : lo, send = s2 ? lo : hi;
            u2[i] = keep + __shfl_xor(send, 4);
        }
        {
            double lo = u2[0], hi = u2[1];
            double keep = s3 ? hi : lo, send = s3 ? lo : hi;
            dtotal = keep + __shfl_xor(send, 8);
        }
        dtot[r] = ((r << 6) + lane < N_LAGS) ? dtotal : -__builtin_inf();
    }
    double dv1 = dtot[0];
    int    di1 = lane;
    #pragma unroll
    for (int r = 1; r < 4; ++r) {
        double c = dtot[r];
        if (c > dv1) { dv1 = c; di1 = (r << 6) + lane; }
    }
    #pragma unroll
    for (int m = 1; m < 64; m <<= 1) {
        double o = __shfl_xor(dv1, m);
        int   oi = __shfl_xor(di1, m);
        if (o > dv1 || (o == dv1 && oi < di1)) { dv1 = o; di1 = oi; }
    }
    if (lane == 0) emit(out, bf, di1);
}

__global__ __launch_bounds__(256, 4) void f0_kernel(const float* __restrict__ wav,
                                                    float* __restrict__ out) {
    // per-wave slice: frame A {ye,yo,le,lo} then frame B {ye,yo,le,lo},
    // 400 dwords each -> 3200 dw = 12.8KB/wave, 51.2KB/block -> 3 blocks/CU
    __shared__ unsigned int yw[WPB][3200];

    const int tid  = threadIdx.x;
    const int wv   = tid >> 6;
    const int lane = tid & 63;
    unsigned int* yeA = yw[wv];
    unsigned int* yoA = yeA + 400;
    unsigned int* leA = yeA + 800;
    unsigned int* loA = yeA + 1200;
    unsigned int* yeB = yeA + 1600;
    unsigned int* yoB = yeA + 2000;
    unsigned int* leB = yeA + 2400;
    unsigned int* loB = yeA + 2800;

    // XCD-contiguous persistent slots: 768 blocks = 8 XCDs * 96. Slot s owns
    // a contiguous run of 6-7 pairs; XCD g covers pairs ~[g*2564,(g+1)*2564)
    // (~2.6MB A-range + mirrored B-range, L2-friendly).
    const int xcd  = blockIdx.x & 7;
    const int idx  = blockIdx.x >> 3;
    const int slot = (xcd * (NBLK / 8) + idx) * WPB + wv;   // [0, 3072)
    int p0, np;
    if (slot < EXTRA) { p0 = slot * 7;                     np = 7; }
    else              { p0 = EXTRA * 7 + (slot - EXTRA)*6; np = 6; }

    const int qd = lane >> 4;       // quad
    const int nn = lane & 15;       // A-row m / B-col n
    const int par = nn & 1;
    const int wA0 = 120 + 4*qd - 8*nn;
    const int wB0 = 136 + 4*qd + ((nn - par) >> 1);
    const int seg = lane & 15;
    const bool oddrow = (lane & 16) != 0;
    const bool hihalf = (lane & 32) != 0;

    for (int t = 0; t < np; ++t) {
        const int pair = p0 + t;
        const int bfA = pair;            // [0, 20512)
        const int bfB = pair + HALF;     // [20512, 41024)
        const int bA  = bfA / N_FRAMES;
        const int fA  = bfA - bA * N_FRAMES;
        const int bB  = bfB / N_FRAMES;
        const int fB  = bfB - bB * N_FRAMES;
        const float* __restrict__ xA = wav + (size_t)bA * T_LEN;
        const float* __restrict__ xB = wav + (size_t)bB * T_LEN;
        const int baseA = fA * HOP - PAD;
        const int baseB = fB * HOP - PAD;
        const bool fastA = (fA != 0 && fA != N_FRAMES - 1);
        const bool fastB = (fB != 0 && fB != N_FRAMES - 1);

        // ---- issue global loads first (both frames) ----
        float4 cA1, cA2, cB1, cB2;
        if (fastA) {
            const float4* g4 = (const float4*)(xA + baseA);
            cA1 = g4[lane];
            cA2 = g4[lane + 64];
        }
        if (fastB) {
            const float4* g4 = (const float4*)(xB + baseB);
            cB1 = g4[lane];
            cB2 = g4[lane + 64];
        }
        // zero margins of both hi-pairs (re-done per iter: tier-3 clobbers)
        yeA[lane] = 0u; yoA[lane] = 0u; yeB[lane] = 0u; yoB[lane] = 0u;
        if (lane < 56) { yeA[64+lane]=0u; yoA[64+lane]=0u; yeB[64+lane]=0u; yoB[64+lane]=0u; }
        if (lane < 25) { yeA[375+lane]=0u; yoA[375+lane]=0u; yeB[375+lane]=0u; yoB[375+lane]=0u; }

        float qenA = 0.0f, qenB = 0.0f;
        if (fastA) {
            qenA = cA1.x*cA1.x + cA1.y*cA1.y + cA1.z*cA1.z + cA1.w*cA1.w
                 + cA2.x*cA2.x + cA2.y*cA2.y + cA2.z*cA2.z + cA2.w*cA2.w;
            write_copies(yeA, yoA, pkh(cA1.x, cA1.y), pkh(cA1.z, cA1.w),
                                   pkh(cA2.x, cA2.y), pkh(cA2.z, cA2.w), lane);
        } else {
            for (int u = lane; u < FRAME_LEN; u += 64) {
                int idxr = baseA + u;
                if (idxr < 0) idxr = -idxr;
                if (idxr >= T_LEN) idxr = 2 * (T_LEN - 1) - idxr;
                float v = xA[idxr];
                qenA = __builtin_fmaf(v, v, qenA);
                unsigned short h = __builtin_bit_cast(unsigned short, (_Float16)v);
                ((unsigned short*)yeA)[240 + u] = h;
                ((unsigned short*)yoA)[239 + u] = h;
            }
        }
        if (fastB) {
            qenB = cB1.x*cB1.x + cB1.y*cB1.y + cB1.z*cB1.z + cB1.w*cB1.w
                 + cB2.x*cB2.x + cB2.y*cB2.y + cB2.z*cB2.z + cB2.w*cB2.w;
            write_copies(yeB, yoB, pkh(cB1.x, cB1.y), pkh(cB1.z, cB1.w),
                                   pkh(cB2.x, cB2.y), pkh(cB2.z, cB2.w), lane);
        } else {
            for (int u = lane; u < FRAME_LEN; u += 64) {
                int idxr = baseB + u;
                if (idxr < 0) idxr = -idxr;
                if (idxr >= T_LEN) idxr = 2 * (T_LEN - 1) - idxr;
                float v = xB[idxr];
                qenB = __builtin_fmaf(v, v, qenB);
                unsigned short h = __builtin_bit_cast(unsigned short, (_Float16)v);
                ((unsigned short*)yeB)[240 + u] = h;
                ((unsigned short*)yoB)[239 + u] = h;
            }
        }
        __threadfence_block();

        qenA = wave_sum(qenA, oddrow, hihalf);
        qenB = wave_sum(qenB, oddrow, hihalf);

        // ---- tier-1: 2x15 MFMA, two frames interleaved (4 acc chains) ----
        const unsigned int* ybhA = par ? yoA : yeA;
        const unsigned int* ybhB = par ? yoB : yeB;
        floatx4 aA0 = {0.f,0.f,0.f,0.f}, aA1 = {0.f,0.f,0.f,0.f};
        floatx4 aB0 = {0.f,0.f,0.f,0.f}, aB1 = {0.f,0.f,0.f,0.f};
        #pragma unroll
        for (int c = 0; c < NC; ++c) {
            uint4 auA = *(const uint4*)(yeA + (wA0 + 16*c));
            const unsigned int* pA = ybhA + (wB0 + 16*c);
            uint4 buA; buA.x = pA[0]; buA.y = pA[1]; buA.z = pA[2]; buA.w = pA[3];
            uint4 auB = *(const uint4*)(yeB + (wA0 + 16*c));
            const unsigned int* pB = ybhB + (wB0 + 16*c);
            uint4 buB; buB.x = pB[0]; buB.y = pB[1]; buB.z = pB[2]; buB.w = pB[3];
            if (c & 1) {
                aA1 = __builtin_amdgcn_mfma_f32_16x16x32_f16(
                    __builtin_bit_cast(half8, auA), __builtin_bit_cast(half8, buA),
                    aA1, 0, 0, 0);
                aB1 = __builtin_amdgcn_mfma_f32_16x16x32_f16(
                    __builtin_bit_cast(half8, auB), __builtin_bit_cast(half8, buB),
                    aB1, 0, 0, 0);
            } else {
                aA0 = __builtin_amdgcn_mfma_f32_16x16x32_f16(
                    __builtin_bit_cast(half8, auA), __builtin_bit_cast(half8, buA),
                    aA0, 0, 0, 0);
                aB0 = __builtin_amdgcn_mfma_f32_16x16x32_f16(
                    __builtin_bit_cast(half8, auB), __builtin_bit_cast(half8, buB),
                    aB0, 0, 0, 0);
            }
        }
        floatx4 accA = aA0 + aA1;
        floatx4 accB = aB0 + aB1;

        float v1A, v2A; int i1A;
        top2_full(accA, qd, nn, oddrow, hihalf, v1A, i1A, v2A);
        float v1B, v2B; int i1B;
        top2_full(accB, qd, nn, oddrow, hihalf, v1B, i1B, v2B);

        const float E1A = 9.765625e-4f * qenA + 0.05f;
        const float E1B = 9.765625e-4f * qenB + 0.05f;
        const bool okA = (v1A - v2A > 2.0f * E1A);
        const bool okB = (v1B - v2B > 2.0f * E1B);

        if (okA) {
            if (lane == 0) emit(out, bfA, i1A);
        }
        if (okB) {
            if (lane == 0) emit(out, bfB, i1B);
        }
        if (!okA)
            finish_frame(xA, baseA, fastA, bfA, out, yeA, yoA, leA, loA,
                         cA1, cA2, accA, qenA, lane, qd, nn, par, wA0, wB0,
                         seg, oddrow, hihalf);
        if (!okB)
            finish_frame(xB, baseB, fastB, bfB, out, yeB, yoB, leB, loB,
                         cB1, cB2, accB, qenB, lane, qd, nn, par, wA0, wB0,
                         seg, oddrow, hihalf);
    }
}

extern "C" void kernel_launch(void* const* d_in, const int* in_sizes, int n_in,
                              void* d_out, int out_size, void* d_ws, size_t ws_size,
                              hipStream_t stream) {
    const float* wav = (const float*)d_in[0]; // (64, 1, 163840) fp32
    float* out = (float*)d_out;               // (64, 641) fp32
    f0_kernel<<<NBLK, 256, 0, stream>>>(wav, out);
}

// Round 6
// 130.959 us; speedup vs baseline: 1.4540x; 1.4540x over previous
//
#include <hip/hip_runtime.h>

// F0 via autocorrelation argmax — round 19: r15 b64-B layout (stride fixed)
//                                           + r16 VALU reductions.
//   SR=16000, HOP=256, FRAME_LEN=512, pad=256, T=163840, B=64, n_frames=641
//   lags p in [32,256). argmax of RAW autocorrelation == reference argmax.
//
// Evidence r13-r18: one-frame-per-wave single-shot (r13/r16, ~70us) beats
// every concurrency restructure (r14 VGPR-cripple, r17 big-LDS one-shot,
// r18 persistent: per-pair latency 4.3->13us under stacked waves). DS-pipe
// service (~600-1000cyc/frame, ~50% busy) remains the only model fitting
// all rounds. r15's b64 B-reads were neutral ONLY because CP=402 (18 mod 32)
// collided bank phases (18s+2h: nn{2,8}{3,9}{6,12}{7,13} dupes -> 6.5M
// conflict cyc == the b64 savings). r19: CP=408 (24 mod 32): 24s+2h takes 16
// DISTINCT even residues over nn=0..15 -> 16 distinct bank-pairs per row,
// <=2-way across quads (free, m136). B: 60 b32 -> 30 b64, conflict-free.
// Reductions stay on VALU (r16): DPP quad_perm/row_ror + permlane16/32_swap
// (fail-safe: wrong orientation inflates v2 -> gates reject -> exact tier-3).
// NC=15 (c=15 B-frags all zero -> +0.0 exactly).
//
// GEMM cast (validated r8-r18, absmax 0.0): y = frame zero-extended,
//   A[m,k]=y[k-16m], B[k,n]=y[k+32+n] => D[m,n]=AC[32+16m+n]
//   15 mfma_f32_16x16x32_f16; staggered copies C_s[e]=y[e-240+s] s=0..3.
// Tiers: E1 = 2^-10*Q + 0.05 ; tier-2 double-f16 split E2 = 1e-4*Q + 0.02 ;
// tier-3 fp64 register tile exact (cold).

#define SR_F 16000.0f
#define HOP 256
#define FRAME_LEN 512
#define PAD 256
#define T_LEN 163840
#define N_FRAMES 641
#define MIN_PERIOD 32
#define N_LAGS 224
#define WPB 4            // waves per block, one frame per wave
#define CP 408           // hi-copy stride in dwords; 408 mod 32 = 24
#define L0_OFF 1632      // lo even copy (4*CP)
#define L1_OFF 2032      // lo odd copy
#define WAVE_DW 2432     // dwords per wave slice (9728 B, 38912 B/block)
#define NC 15            // K-steps: c=15 contributes exactly zero

typedef _Float16 half8 __attribute__((ext_vector_type(8)));
typedef float floatx4 __attribute__((ext_vector_type(4)));
typedef unsigned int uint2v __attribute__((ext_vector_type(2)));

__device__ __forceinline__ int swz(int q) { return q ^ ((q >> 3) & 7); }

__device__ __forceinline__ unsigned int pkh(float a, float b) {
    unsigned short ha = __builtin_bit_cast(unsigned short, (_Float16)a);
    unsigned short hb = __builtin_bit_cast(unsigned short, (_Float16)b);
    return (unsigned int)ha | ((unsigned int)hb << 16);
}

// ---- cross-lane on the VALU pipe (keep the DS unit free) ----
#define DPP_XOR1 0xB1    // quad_perm [1,0,3,2]
#define DPP_XOR2 0x4E    // quad_perm [2,3,0,1]
#define DPP_ROR4 0x124   // row_ror:4
#define DPP_ROR8 0x128   // row_ror:8

template <int CTRL> __device__ __forceinline__ int dppi(int x) {
    return __builtin_amdgcn_update_dpp(0, x, CTRL, 0xF, 0xF, false);
}
template <int CTRL> __device__ __forceinline__ float dppf(float x) {
    return __builtin_bit_cast(float, dppi<CTRL>(__builtin_bit_cast(int, x)));
}

// permlane swaps: contract — pr[0]+pr[1] == self+partner;
// (sel ? pr[0] : pr[1]) == partner, sel = oddrow (16) / upper half (32).
__device__ __forceinline__ uint2v pl16sw(unsigned int x, bool sel) {
#if __has_builtin(__builtin_amdgcn_permlane16_swap)
    (void)sel;
    return __builtin_amdgcn_permlane16_swap(x, x, false, false);
#else
    unsigned int p = (unsigned int)__shfl_xor((int)x, 16);
    uint2v r; r[0] = sel ? p : x; r[1] = sel ? x : p; return r;
#endif
}
__device__ __forceinline__ uint2v pl32sw(unsigned int x, bool sel) {
#if __has_builtin(__builtin_amdgcn_permlane32_swap)
    (void)sel;
    return __builtin_amdgcn_permlane32_swap(x, x, false, false);
#else
    unsigned int p = (unsigned int)__shfl_xor((int)x, 32);
    uint2v r; r[0] = sel ? p : x; r[1] = sel ? x : p; return r;
#endif
}

// full-wave sum, zero DS ops
__device__ __forceinline__ float wave_sum(float x, bool oddrow, bool hihalf) {
    x += dppf<DPP_XOR1>(x);
    x += dppf<DPP_XOR2>(x);
    x += dppf<DPP_ROR4>(x);
    x += dppf<DPP_ROR8>(x);
    uint2v p = pl16sw(__builtin_bit_cast(unsigned int, x), oddrow);
    x = __builtin_bit_cast(float, p[0]) + __builtin_bit_cast(float, p[1]);
    p = pl32sw(__builtin_bit_cast(unsigned int, x), hihalf);
    x = __builtin_bit_cast(float, p[0]) + __builtin_bit_cast(float, p[1]);
    return x;
}

__device__ __forceinline__
void top2_comb(float& v1, int& i1, float& v2, float ov1, int oi1, float ov2) {
    bool take = (ov1 > v1) || (ov1 == v1 && oi1 < i1);
    float lose = take ? v1 : ov1;
    if (take) { v1 = ov1; i1 = oi1; }
    v2 = fmaxf(fmaxf(v2, ov2), lose);
}

template <int CTRL> __device__ __forceinline__
void top2_dpp(float& v1, int& i1, float& v2) {
    float ov1 = dppf<CTRL>(v1);
    int   oi1 = dppi<CTRL>(i1);
    float ov2 = dppf<CTRL>(v2);
    top2_comb(v1, i1, v2, ov1, oi1, ov2);
}

// per-lane top2 over 4 regs, then full-wave combine — zero DS ops
__device__ __forceinline__
void top2_full(floatx4 acc, int qd, int nn, bool oddrow, bool hihalf,
               float& v1, int& i1, float& v2) {
    v1 = acc[0];
    i1 = 64*qd + nn;
    v2 = -__builtin_inff();
    #pragma unroll
    for (int r = 1; r < 4; ++r) {
        float cv = (4*qd + r < 14) ? acc[r] : -__builtin_inff();
        bool take = (cv > v1);
        float lose = take ? v1 : cv;
        if (take) { v1 = cv; i1 = 64*qd + 16*r + nn; }
        v2 = fmaxf(v2, lose);
    }
    top2_dpp<DPP_XOR1>(v1, i1, v2);
    top2_dpp<DPP_XOR2>(v1, i1, v2);
    top2_dpp<DPP_ROR4>(v1, i1, v2);
    top2_dpp<DPP_ROR8>(v1, i1, v2);
    {   // stage 16 via permlane16_swap
        uint2v a = pl16sw(__builtin_bit_cast(unsigned int, v1), oddrow);
        uint2v b = pl16sw((unsigned int)i1, oddrow);
        uint2v c = pl16sw(__builtin_bit_cast(unsigned int, v2), oddrow);
        float ov1 = __builtin_bit_cast(float, oddrow ? a[0] : a[1]);
        int   oi1 = (int)(oddrow ? b[0] : b[1]);
        float ov2 = __builtin_bit_cast(float, oddrow ? c[0] : c[1]);
        top2_comb(v1, i1, v2, ov1, oi1, ov2);
    }
    {   // stage 32 via permlane32_swap
        uint2v a = pl32sw(__builtin_bit_cast(unsigned int, v1), hihalf);
        uint2v b = pl32sw((unsigned int)i1, hihalf);
        uint2v c = pl32sw(__builtin_bit_cast(unsigned int, v2), hihalf);
        float ov1 = __builtin_bit_cast(float, hihalf ? a[0] : a[1]);
        int   oi1 = (int)(hihalf ? b[0] : b[1]);
        float ov2 = __builtin_bit_cast(float, hihalf ? c[0] : c[1]);
        top2_comb(v1, i1, v2, ov1, oi1, ov2);
    }
}

// stage 4 staggered hi copies: C_s[e] = y[e-240+s], s=0..3 (validated r15)
__device__ __forceinline__ void write_hi4(unsigned int* c0_, unsigned int* c1_,
                                          unsigned int* c2_, unsigned int* c3_,
                                          unsigned int u10, unsigned int u11,
                                          unsigned int u20, unsigned int u21,
                                          int lane) {
    *(unsigned long long*)(c0_ + 120 + 2*lane) =
        ((unsigned long long)u11 << 32) | u10;
    *(unsigned long long*)(c0_ + 248 + 2*lane) =
        ((unsigned long long)u21 << 32) | u20;
    unsigned int a  = __shfl(u10, (lane + 1) & 63);
    unsigned int bb = __shfl(u20, (lane + 1) & 63);
    unsigned int n1 = (lane == 63) ? bb : a;
    unsigned int n2 = (lane == 63) ? 0u : bb;
    unsigned int o10 = (u10 >> 16) | (u11 << 16);
    unsigned int o11 = (u11 >> 16) | (n1 << 16);
    unsigned int o20 = (u20 >> 16) | (u21 << 16);
    unsigned int o21 = (u21 >> 16) | (n2 << 16);
    *(unsigned long long*)(c1_ + 120 + 2*lane) =
        ((unsigned long long)o11 << 32) | o10;
    *(unsigned long long*)(c1_ + 248 + 2*lane) =
        ((unsigned long long)o21 << 32) | o20;
    // C2 = C0 data one dword earlier (adjacent pairs -> ds_write2_b32)
    c2_[119 + 2*lane] = u10; c2_[120 + 2*lane] = u11;
    c2_[247 + 2*lane] = u20; c2_[248 + 2*lane] = u21;
    // C3 = C1 data one dword earlier
    c3_[119 + 2*lane] = o10; c3_[120 + 2*lane] = o11;
    c3_[247 + 2*lane] = o20; c3_[248 + 2*lane] = o21;
}

// stage lo parity copies (tier-2 only): L0[e]=y[e-240], L1[e]=y[e-239]
__device__ __forceinline__ void write_lo2(unsigned int* l0_, unsigned int* l1_,
                                          unsigned int u10, unsigned int u11,
                                          unsigned int u20, unsigned int u21,
                                          int lane) {
    *(unsigned long long*)(l0_ + 120 + 2*lane) =
        ((unsigned long long)u11 << 32) | u10;
    *(unsigned long long*)(l0_ + 248 + 2*lane) =
        ((unsigned long long)u21 << 32) | u20;
    unsigned int a  = __shfl(u10, (lane + 1) & 63);
    unsigned int bb = __shfl(u20, (lane + 1) & 63);
    unsigned int n1 = (lane == 63) ? bb : a;
    unsigned int n2 = (lane == 63) ? 0u : bb;
    *(unsigned long long*)(l1_ + 120 + 2*lane) =
        ((unsigned long long)(((u11 >> 16) | (n1 << 16))) << 32) |
        ((u10 >> 16) | (u11 << 16));
    *(unsigned long long*)(l1_ + 248 + 2*lane) =
        ((unsigned long long)(((u21 >> 16) | (n2 << 16))) << 32) |
        ((u20 >> 16) | (u21 << 16));
}

__global__ __launch_bounds__(256, 4) void f0_kernel(const float* __restrict__ wav,
                                                    float* __restrict__ out) {
    __shared__ unsigned int yw[WPB][WAVE_DW];   // 38912 B/block -> 4 blocks/CU

    const int tid  = threadIdx.x;
    const int wv   = tid >> 6;
    const int lane = tid & 63;
    unsigned int* c0p = yw[wv];
    unsigned int* c1p = c0p + CP;
    unsigned int* c2p = c0p + 2*CP;
    unsigned int* c3p = c0p + 3*CP;
    unsigned int* l0p = c0p + L0_OFF;
    unsigned int* l1p = c0p + L1_OFF;

    // XCD-contiguous frame assignment: 10256 blocks = 8*1282.
    const int xcd = blockIdx.x & 7;
    const int idx = blockIdx.x >> 3;
    const int bf  = (xcd * 1282 + idx) * WPB + wv;   // all 41024 covered
    const int b   = bf / N_FRAMES;
    const int f   = bf - b * N_FRAMES;
    const float* __restrict__ x = wav + (size_t)b * T_LEN;
    const int base = f * HOP - PAD;
    const bool fast = (f != 0 && f != N_FRAMES - 1);

    const int qd = lane >> 4;       // quad
    const int nn = lane & 15;       // A-row m / B-col n
    const int par = nn & 1;
    const int wA0 = 120 + 4*qd - 8*nn;                       // C0/L0, 16B align
    // hi B base: copy s=nn&3; bank phase 24s+2h distinct over nn (CP=408)
    const unsigned int* bhp = c0p + CP*(nn & 3) + 136 + 4*qd + 2*(nn >> 2);
    const int wB0old = 136 + 4*qd + ((nn - par) >> 1);       // lo parity copies
    const int seg = lane & 15;
    const bool s0 = (seg & 1), s1 = (seg & 2), s2 = (seg & 4), s3 = (seg & 8);
    const bool oddrow = (lane & 16) != 0;
    const bool hihalf = (lane & 32) != 0;

    // ---- issue global loads first ----
    float4 c1, c2;
    if (fast) {
        const float4* g4 = (const float4*)(x + base);   // aligned, in-bounds
        c1 = g4[lane];
        c2 = g4[lane + 64];
    }
    // one-time margin zeros (payloads rewritten below; same-wave DS order).
    // bottoms: only C0/L0 are read below dword 120 (A-reads); B-reads >=136.
    for (int d = lane; d < 120; d += 64) { c0p[d] = 0u; l0p[d] = 0u; }
    if (lane < 28) {
        int d = 374 + lane;
        c0p[d] = 0u; c1p[d] = 0u; c2p[d] = 0u; c3p[d] = 0u;
        l0p[d] = 0u; l1p[d] = 0u;
    }

    float qen = 0.0f;
    if (fast) {
        qen = c1.x*c1.x + c1.y*c1.y + c1.z*c1.z + c1.w*c1.w
            + c2.x*c2.x + c2.y*c2.y + c2.z*c2.z + c2.w*c2.w;
        write_hi4(c0p, c1p, c2p, c3p, pkh(c1.x, c1.y), pkh(c1.z, c1.w),
                                      pkh(c2.x, c2.y), pkh(c2.z, c2.w), lane);
    } else {
        for (int t = lane; t < FRAME_LEN; t += 64) {
            int idxr = base + t;
            if (idxr < 0) idxr = -idxr;
            if (idxr >= T_LEN) idxr = 2 * (T_LEN - 1) - idxr;
            float v = x[idxr];
            qen = __builtin_fmaf(v, v, qen);
            unsigned short h = __builtin_bit_cast(unsigned short, (_Float16)v);
            ((unsigned short*)c0p)[240 + t] = h;
            ((unsigned short*)c1p)[239 + t] = h;
            ((unsigned short*)c2p)[238 + t] = h;
            ((unsigned short*)c3p)[237 + t] = h;
        }
    }
    __threadfence_block();

    qen = wave_sum(qen, oddrow, hihalf);

    // ---------------- tier-1: 15 MFMA (2 chains), b64 B-reads ----------------
    floatx4 acc0 = {0.f, 0.f, 0.f, 0.f};
    floatx4 acc1 = {0.f, 0.f, 0.f, 0.f};
    #pragma unroll
    for (int c = 0; c < NC; ++c) {
        uint4 au = *(const uint4*)(c0p + (wA0 + 16*c));
        unsigned long long bl = *(const unsigned long long*)(bhp + 16*c);
        unsigned long long br = *(const unsigned long long*)(bhp + 16*c + 2);
        uint4 bu; bu.x = (unsigned int)bl; bu.y = (unsigned int)(bl >> 32);
        bu.z = (unsigned int)br; bu.w = (unsigned int)(br >> 32);
        if (c & 1)
            acc1 = __builtin_amdgcn_mfma_f32_16x16x32_f16(
                __builtin_bit_cast(half8, au), __builtin_bit_cast(half8, bu),
                acc1, 0, 0, 0);
        else
            acc0 = __builtin_amdgcn_mfma_f32_16x16x32_f16(
                __builtin_bit_cast(half8, au), __builtin_bit_cast(half8, bu),
                acc0, 0, 0, 0);
    }
    floatx4 acc = acc0 + acc1;

    float v1, v2; int i1;
    top2_full(acc, qd, nn, oddrow, hihalf, v1, i1, v2);

    const float E1 = 9.765625e-4f * qen + 0.05f;
    if (v1 - v2 > 2.0f * E1) {
        if (lane == 0) {
            float period = (float)(i1 + MIN_PERIOD);
            float f0 = SR_F / (period + 1e-8f);
            out[bf] = fminf(fmaxf(f0, 50.0f), 500.0f);
        }
        return;
    }

    // ==== tier-2: double-f16 split, +30 MFMA (hi*lo + lo*hi), ~15% ====
    if (fast) {
        float l0 = c1.x - (float)(_Float16)c1.x;
        float l1 = c1.y - (float)(_Float16)c1.y;
        float l2 = c1.z - (float)(_Float16)c1.z;
        float l3 = c1.w - (float)(_Float16)c1.w;
        float l4 = c2.x - (float)(_Float16)c2.x;
        float l5 = c2.y - (float)(_Float16)c2.y;
        float l6 = c2.z - (float)(_Float16)c2.z;
        float l7 = c2.w - (float)(_Float16)c2.w;
        write_lo2(l0p, l1p, pkh(l0, l1), pkh(l2, l3),
                            pkh(l4, l5), pkh(l6, l7), lane);
    } else {
        for (int t = lane; t < FRAME_LEN; t += 64) {
            int idxr = base + t;
            if (idxr < 0) idxr = -idxr;
            if (idxr >= T_LEN) idxr = 2 * (T_LEN - 1) - idxr;
            float v = x[idxr];
            float l = v - (float)(_Float16)v;
            unsigned short h = __builtin_bit_cast(unsigned short, (_Float16)l);
            ((unsigned short*)l0p)[240 + t] = h;
            ((unsigned short*)l1p)[239 + t] = h;
        }
    }
    __threadfence_block();

    const unsigned int* ybl = par ? l1p : l0p;
    #pragma unroll
    for (int c = 0; c < NC; ++c) {              // hi * lo
        uint4 au = *(const uint4*)(c0p + (wA0 + 16*c));
        const unsigned int* p = ybl + (wB0old + 16*c);
        uint4 bu; bu.x = p[0]; bu.y = p[1]; bu.z = p[2]; bu.w = p[3];
        acc = __builtin_amdgcn_mfma_f32_16x16x32_f16(
            __builtin_bit_cast(half8, au), __builtin_bit_cast(half8, bu),
            acc, 0, 0, 0);
    }
    #pragma unroll
    for (int c = 0; c < NC; ++c) {              // lo * hi
        uint4 au = *(const uint4*)(l0p + (wA0 + 16*c));
        unsigned long long bl = *(const unsigned long long*)(bhp + 16*c);
        unsigned long long br = *(const unsigned long long*)(bhp + 16*c + 2);
        uint4 bu; bu.x = (unsigned int)bl; bu.y = (unsigned int)(bl >> 32);
        bu.z = (unsigned int)br; bu.w = (unsigned int)(br >> 32);
        acc = __builtin_amdgcn_mfma_f32_16x16x32_f16(
            __builtin_bit_cast(half8, au), __builtin_bit_cast(half8, bu),
            acc, 0, 0, 0);
    }

    top2_full(acc, qd, nn, oddrow, hihalf, v1, i1, v2);

    const float E2 = 1.0e-4f * qen + 0.02f;
    if (v1 - v2 > 2.0f * E2) {
        if (lane == 0) {
            float period = (float)(i1 + MIN_PERIOD);
            float f0 = SR_F / (period + 1e-8f);
            out[bf] = fminf(fmaxf(f0, 50.0f), 500.0f);
        }
        return;
    }

    // ============ tier-3: fp64 register tile (exact), ~1-2% ============
    float* sw = (float*)c0p;   // 576 floats over C0/C1 region (terminal use)
    if (fast) {
        const float4* g4 = (const float4*)(x + base);   // L2-hot reload
        ((float4*)sw)[swz(lane)]      = g4[lane];
        ((float4*)sw)[swz(lane + 64)] = g4[lane + 64];
        if (lane < 16) ((float4*)sw)[swz(lane + 128)] = make_float4(0.f,0.f,0.f,0.f);
    } else {
        for (int t = lane; t < FRAME_LEN; t += 64) {
            int idxr = base + t;
            if (idxr < 0) idxr = -idxr;
            if (idxr >= T_LEN) idxr = 2 * (T_LEN - 1) - idxr;
            sw[(swz(t >> 2) << 2) | (t & 3)] = x[idxr];
        }
        int t = FRAME_LEN + lane;
        sw[(swz(t >> 2) << 2) | (t & 3)] = 0.0f;
    }
    __threadfence_block();

    const float4* s4 = (const float4*)sw;
    double dtot[4];
    #pragma unroll
    for (int r = 0; r < 4; ++r) {
        const int g  = (r << 2) + qd;
        const int p0 = MIN_PERIOD + (g << 4);
        double dacc[16];
        #pragma unroll
        for (int j = 0; j < 16; ++j) dacc[j] = 0.0;
        if (g < 14) {
            const int n16 = (FRAME_LEN - p0 + 15) >> 4;
            #pragma unroll
            for (int k = 0; k < 2; ++k) {
                const int ch = seg + (k << 4);
                if (ch < n16) {
                    const int t  = ch << 4;
                    const int qa = t >> 2;
                    const int qw = (t + p0) >> 2;
                    float a[16], w[32];
                    #pragma unroll
                    for (int u = 0; u < 4; ++u) {
                        float4 v = s4[swz(qa + u)];
                        a[4*u+0]=v.x; a[4*u+1]=v.y; a[4*u+2]=v.z; a[4*u+3]=v.w;
                    }
                    #pragma unroll
                    for (int u = 0; u < 8; ++u) {
                        float4 v = s4[swz(qw + u)];
                        w[4*u+0]=v.x; w[4*u+1]=v.y; w[4*u+2]=v.z; w[4*u+3]=v.w;
                    }
                    #pragma unroll
                    for (int j = 0; j < 16; ++j) {
                        #pragma unroll
                        for (int i = 0; i < 16; ++i)
                            dacc[j] = fma((double)a[i], (double)w[i + j], dacc[j]);
                    }
                }
            }
        }
        double u8[8], u4[4], u2[2], dtotal;
        #pragma unroll
        for (int i = 0; i < 8; ++i) {
            double lo = dacc[2*i], hi = dacc[2*i+1];
            double keep = s0 ? hi : lo, send = s0 ? lo : hi;
            u8[i] = keep + __shfl_xor(send, 1);
        }
        #pragma unroll
        for (int i = 0; i < 4; ++i) {
            double lo = u8[2*i], hi = u8[2*i+1];
            double keep = s1 ? hi : lo, send = s1 ? lo : hi;
            u4[i] = keep + __shfl_xor(send, 2);
        }
        #pragma unroll
        for (int i = 0; i < 2; ++i) {
            double lo = u4[2*i], hi = u4[2*i+1];
            double keep = s2 ? hi : lo, send = s2 ? lo : hi;
            u2[i] = keep + __shfl_xor(send, 4);
        }
        {
            double lo = u2[0], hi = u2[1];
            double keep = s3 ? hi : lo, send = s3 ? lo : hi;
            dtotal = keep + __shfl_xor(send, 8);
        }
        dtot[r] = ((r << 6) + lane < N_LAGS) ? dtotal : -__builtin_inf();
    }
    double dv1 = dtot[0];
    int    di1 = lane;
    #pragma unroll
    for (int r = 1; r < 4; ++r) {
        double c = dtot[r];
        if (c > dv1) { dv1 = c; di1 = (r << 6) + lane; }
    }
    #pragma unroll
    for (int m = 1; m < 64; m <<= 1) {
        double o = __shfl_xor(dv1, m);
        int   oi = __shfl_xor(di1, m);
        if (o > dv1 || (o == dv1 && oi < di1)) { dv1 = o; di1 = oi; }
    }
    if (lane == 0) {
        float period = (float)(di1 + MIN_PERIOD);
        float f0 = SR_F / (period + 1e-8f);
        out[bf] = fminf(fmaxf(f0, 50.0f), 500.0f);
    }
}

extern "C" void kernel_launch(void* const* d_in, const int* in_sizes, int n_in,
                              void* d_out, int out_size, void* d_ws, size_t ws_size,
                              hipStream_t stream) {
    const float* wav = (const float*)d_in[0]; // (64, 1, 163840) fp32
    float* out = (float*)d_out;               // (64, 641) fp32
    const int n_blocks = (64 * N_FRAMES) / WPB;   // 10256 = 8 * 1282
    f0_kernel<<<n_blocks, 256, 0, stream>>>(wav, out);
}